// Round 2
// baseline (407.123 us; speedup 1.0000x reference)
//
#include <hip/hip_runtime.h>
#include <hip/hip_bf16.h>
#include <math.h>

// Problem: Attention_58102317580396
// B=2, S=2048, D=2048, H=16, DH=128. Inputs/outputs FP32; internal bf16 MFMA.
// Pipeline: cvt(x,w_in,w_out)->bf16 ; GEMM1 x@w_in^T -> P[4096][6144] ;
//           flash attn -> O[4096][2048] ; GEMM2 O@w_out^T -> out fp32.
// R10: gemm256 schedule polish (R9 regressed 125->145us; true MFMA duty ~10%,
// ~1360 cyc/phase vs m201's ~825):
//   (1) sched_barrier(0) before the phase's first s_barrier so ds_read/GLDS
//       issues stay ABOVE the barrier (overlap ds latency with barrier wait);
//   (2) stages moved to earliest-legal slots -> uniform 5-phase vmcnt windows
//       (waits vmcnt 12/8/12/8 at ph1/3/5/7 instead of 6/6 at ph3/7);
//   (3) ks-outer MFMA order (8 independent MFMAs between acc-dependent pairs).
// Stage deadness (buf being overwritten): B dead after ph0 of its tile's
// compute; A-H1 (rows 0-63,128-191) after ph1; A-H2 (64-127,192-255) after
// ph3. Schedule per iter (tiles t->buf0 ph0-3, t+1->buf1 ph4-7):
//   ph0: H2(t+1)->b1 | ph1: B(t+2)->b0 x4 | ph2: H1(t+2)->b0 | ph3: -
//   ph4: H2(t+2)->b0 | ph5: B(t+3)->b1 x4 | ph6: H1(t+3)->b1 | ph7: -
// attn + gemm_bt<64> (GEMM2) unchanged.
// Verified layouts (learn_hip m89/m120):
//   A-frag: m=lane&15, k=quad*8+j ; B-frag: n=lane&15, k=quad*8+j (same addr)
//   C/D:    col=lane&15, row=quad*4+reg

typedef short bf16x8 __attribute__((ext_vector_type(8)));
typedef float f32x4 __attribute__((ext_vector_type(4)));

#define NEG_BIG -30000.0f

__device__ __forceinline__ short f2bf(float f) {
    union { float f; unsigned u; } v; v.f = f;
    unsigned r = v.u + 0x7fffu + ((v.u >> 16) & 1u);  // RNE
    return (short)(r >> 16);
}

__device__ __forceinline__ int pack2bf(float a, float b) {
    return (int)((((unsigned)f2bf(b)) << 16) | (((unsigned)f2bf(a)) & 0xffffu));
}

#define GLDS16(g, l) \
    __builtin_amdgcn_global_load_lds((const __attribute__((address_space(1))) void*)(g), \
                                     (__attribute__((address_space(3))) void*)(l), 16, 0, 0)

// fp32 -> bf16 elementwise (n divisible by 1024)
__global__ __launch_bounds__(256) void cvt_f32_bf16(const float* __restrict__ src,
                                                    short* __restrict__ dst, int n) {
    int i = (blockIdx.x * blockDim.x + threadIdx.x) * 4;
    if (i < n) {
        float4 v = *(const float4*)(src + i);
        short4 o;
        o.x = f2bf(v.x); o.y = f2bf(v.y); o.z = f2bf(v.z); o.w = f2bf(v.w);
        *(short4*)(dst + i) = o;
    }
}

// ---------------------------------------------------------------------------
// Legacy 128-tile GEMM (kept for GEMM2): C[M][N] = A[M][K] * B[N][K]^T
// block 256 = 4 waves; block tile 128xBN; wave tile 64x(BN/2); BK=64.
template <int BN, bool F32OUT>
__global__ __launch_bounds__(256) void gemm_bt(const short* __restrict__ A,
                                               const short* __restrict__ Bm,
                                               void* __restrict__ Cv,
                                               int N, int K) {
    constexpr int NT = BN / 32;               // n-acc tiles per wave
    constexpr int SUBA = 128 * 32;            // shorts per A sub-tile
    constexpr int SUBB = BN * 32;             // shorts per B sub-tile
    __shared__ short sA[2 * SUBA];
    __shared__ short sB[2 * SUBB];
    const int lane = threadIdx.x & 63;
    const int w = threadIdx.x >> 6;
    const int l15 = lane & 15, quad = lane >> 4;
    const int bm0 = blockIdx.y * 128, bn0 = blockIdx.x * BN;

    const int c1 = w * 64 + lane;             // chunk id 0..255
    const short* gA = A + (size_t)(bm0 + (c1 >> 2)) * K + (c1 & 3) * 8;
    const short* gB = Bm + (size_t)(bn0 + (c1 >> 2)) * K + (c1 & 3) * 8;
    const size_t half64 = (size_t)64 * K;     // chunk +256 -> row +64
    short* lA1 = sA + w * 512;                // wave-uniform GLDS bases
    short* lA2 = sA + 2048 + w * 512;
    short* lB1 = sB + w * 512;
    short* lB2 = sB + 2048 + w * 512;         // only when BN==128

    const int wm = (w >> 1) * 64, wn = (w & 1) * (BN / 2);
    const short* pa = sA + (wm + l15) * 32 + quad * 8;
    const short* pb = sB + (wn + l15) * 32 + quad * 8;

    f32x4 acc[4][NT] = {};
    for (int k0 = 0; k0 < K; k0 += 64) {
        #pragma unroll
        for (int s = 0; s < 2; s++) {
            const int ks = k0 + s * 32;
            GLDS16(gA + ks, lA1 + s * SUBA);
            GLDS16(gA + half64 + ks, lA2 + s * SUBA);
            GLDS16(gB + ks, lB1 + s * SUBB);
            if constexpr (BN == 128) GLDS16(gB + half64 + ks, lB2 + s * SUBB);
        }
        __syncthreads();
        #pragma unroll
        for (int s = 0; s < 2; s++) {
            bf16x8 af[4], bf[NT];
            #pragma unroll
            for (int mt = 0; mt < 4; mt++) af[mt] = *(const bf16x8*)(pa + s * SUBA + mt * 512);
            #pragma unroll
            for (int nt = 0; nt < NT; nt++) bf[nt] = *(const bf16x8*)(pb + s * SUBB + nt * 512);
            #pragma unroll
            for (int mt = 0; mt < 4; mt++)
                #pragma unroll
                for (int nt = 0; nt < NT; nt++)
                    acc[mt][nt] = __builtin_amdgcn_mfma_f32_16x16x32_bf16(af[mt], bf[nt], acc[mt][nt], 0, 0, 0);
        }
        __syncthreads();
    }
    #pragma unroll
    for (int mt = 0; mt < 4; mt++)
        #pragma unroll
        for (int nt = 0; nt < NT; nt++)
            #pragma unroll
            for (int r = 0; r < 4; r++) {
                int row = bm0 + wm + mt * 16 + quad * 4 + r;
                int col = bn0 + wn + nt * 16 + l15;
                if (F32OUT)
                    ((float*)Cv)[(size_t)row * N + col] = acc[mt][nt][r];
                else
                    ((short*)Cv)[(size_t)row * N + col] = f2bf(acc[mt][nt][r]);
            }
}

// ---------------------------------------------------------------------------
// 256x256 8-phase GEMM (m201 structure). C[M][N] = A[M][K] * B[N][K]^T.
// 512 threads = 8 waves (2M x 4N). BK=64 (2 k-subtiles of 32). Requires:
// M%256==0, N%256==0, K%128==0, K>=256, grid flat = (M/256)*(N/256), %8==0.
// LDS per operand buffer: [256 rows][64 cols] bf16, row pitch 128 B = 8
// 16B-slots; swizzle slot ^= (row&7), applied on the global SOURCE column
// (linear global_load_lds dest) and on ds_read addresses (both-sides rule).
struct MainT { static constexpr bool value = false; };
struct TailT { static constexpr bool value = true; };

template <bool F32OUT>
__global__ __launch_bounds__(512, 2) void gemm256(const short* __restrict__ A,
                                                  const short* __restrict__ Bm,
                                                  void* __restrict__ Cv,
                                                  int N, int K, int MT) {
    __shared__ short sA[2][256 * 64];
    __shared__ short sB[2][256 * 64];
    const int tid = threadIdx.x;
    const int lane = tid & 63, w = tid >> 6;
    const int l15 = lane & 15, quad = lane >> 4;
    const int wm = w >> 2, wn = w & 3;

    // bijective XCD swizzle (gridDim.x % 8 == 0); m-fastest decomposition so
    // an XCD's resident blocks share B-panels in its private L2.
    const int cpx = (int)gridDim.x >> 3;
    const int swz = ((int)blockIdx.x & 7) * cpx + ((int)blockIdx.x >> 3);
    const int bm0 = (swz % MT) * 256;
    const int bn0 = (swz / MT) * 256;

    // Staging: lane covers LDS (row = w*8 + lane/8, slot = lane&7) of a
    // 64-row chunk; source column pre-swizzled: slot ^ (row&7).
    const int rloc = w * 8 + (lane >> 3);
    const int csw = ((lane & 7) ^ ((lane >> 3) & 7)) * 8;  // elements
    const short* gA = A + (size_t)(bm0 + rloc) * K + csw;
    const short* gB = Bm + (size_t)(bn0 + rloc) * K + csw;

    auto stA = [&](int buf, int R0, int t) {
        GLDS16(gA + (size_t)R0 * K + t * 64, &sA[buf][R0 * 64 + w * 512]);
    };
    auto stB = [&](int buf, int R0, int t) {
        GLDS16(gB + (size_t)R0 * K + t * 64, &sB[buf][R0 * 64 + w * 512]);
    };

    const int sx = l15 & 7;  // read-side slot XOR (row&7 == l15&7 everywhere)
    auto ldA = [&](int buf, int r0, int ks) -> bf16x8 {
        const int off = (r0 + l15) * 128 + (((ks * 4 + quad) ^ sx) << 4);
        return *(const bf16x8*)((const char*)&sA[buf][0] + off);
    };
    auto ldB = [&](int buf, int r0, int ks) -> bf16x8 {
        const int off = (r0 + l15) * 128 + (((ks * 4 + quad) ^ sx) << 4);
        return *(const bf16x8*)((const char*)&sB[buf][0] + off);
    };

    f32x4 acc[8][4] = {};
    bf16x8 bfr[4][2];

    // Prologue: tile0 fully -> buf0 ; tile1 B,H1 -> buf1 (14 loads/wave);
    // vmcnt(6) -> tile0's 8 oldest complete, 3 half-tiles in flight.
    stB(0, 0, 0); stB(0, 64, 0); stB(0, 128, 0); stB(0, 192, 0);
    stA(0, 0, 0); stA(0, 128, 0); stA(0, 64, 0); stA(0, 192, 0);
    stB(1, 0, 1); stB(1, 64, 1); stB(1, 128, 1); stB(1, 192, 1);
    stA(1, 0, 1); stA(1, 128, 1);
    asm volatile("s_waitcnt vmcnt(6)" ::: "memory");
    __builtin_amdgcn_s_barrier();

    auto iter = [&](auto TC, int t0) {
        constexpr bool TAIL = decltype(TC)::value;
        #pragma unroll
        for (int tt = 0; tt < 2; ++tt) {
            const int buf = tt;  // tile t0+tt -> buf (tile parity)
            #pragma unroll
            for (int q = 0; q < 4; ++q) {
                const int ph = tt * 4 + q;
                bf16x8 afr[2][2];
                if (q == 0) {  // 8 B-frag ds_reads, reused across 4 phases
                    #pragma unroll
                    for (int nt = 0; nt < 4; ++nt)
                        #pragma unroll
                        for (int ks = 0; ks < 2; ++ks)
                            bfr[nt][ks] = ldB(buf, wn * 64 + nt * 16, ks);
                }
                #pragma unroll
                for (int mt = 0; mt < 2; ++mt)
                    #pragma unroll
                    for (int ks = 0; ks < 2; ++ks)
                        afr[mt][ks] = ldA(buf, wm * 128 + q * 32 + mt * 16, ks);
                // stages at earliest-legal slots (deadness: see header comment)
                if (ph == 0) { stA(1, 64, t0 + 1); stA(1, 192, t0 + 1); }  // H2(t+1)
                if constexpr (!TAIL) {
                    if (ph == 1) { stB(0, 0, t0 + 2); stB(0, 64, t0 + 2);
                                   stB(0, 128, t0 + 2); stB(0, 192, t0 + 2); }  // B(t+2)
                    if (ph == 2) { stA(0, 0, t0 + 2); stA(0, 128, t0 + 2); }    // H1(t+2)
                    if (ph == 4) { stA(0, 64, t0 + 2); stA(0, 192, t0 + 2); }   // H2(t+2)
                    if (ph == 5) { stB(1, 0, t0 + 3); stB(1, 64, t0 + 3);
                                   stB(1, 128, t0 + 3); stB(1, 192, t0 + 3); }  // B(t+3)
                    if (ph == 6) { stA(1, 0, t0 + 3); stA(1, 128, t0 + 3); }    // H1(t+3)
                }
                __builtin_amdgcn_sched_barrier(0);  // keep ds/GLDS issues above barrier
                __builtin_amdgcn_s_barrier();
                asm volatile("s_waitcnt lgkmcnt(0)" ::: "memory");
                __builtin_amdgcn_sched_barrier(0);  // rule #18: pin MFMA after wait
                __builtin_amdgcn_s_setprio(1);
                #pragma unroll
                for (int ks = 0; ks < 2; ++ks)      // ks-outer: indep MFMA runs
                    #pragma unroll
                    for (int mt = 0; mt < 2; ++mt)
                        #pragma unroll
                        for (int nt = 0; nt < 4; ++nt)
                            acc[q * 2 + mt][nt] = __builtin_amdgcn_mfma_f32_16x16x32_bf16(
                                afr[mt][ks], bfr[nt][ks], acc[q * 2 + mt][nt], 0, 0, 0);
                __builtin_amdgcn_s_setprio(0);
                __builtin_amdgcn_sched_barrier(0);
                // counted waits, 5-phase windows (issue->wait) everywhere
                if constexpr (!TAIL) {
                    if (ph == 1 || ph == 5) asm volatile("s_waitcnt vmcnt(12)" ::: "memory");
                    if (ph == 3 || ph == 7) asm volatile("s_waitcnt vmcnt(8)" ::: "memory");
                } else {
                    if (ph == 3) asm volatile("s_waitcnt vmcnt(0)" ::: "memory");
                }
                __builtin_amdgcn_s_barrier();
            }
        }
    };

    const int NTt = K >> 6;  // K-tiles (even, >= 4)
    int t0 = 0;
    for (; t0 < NTt - 2; t0 += 2) iter(MainT{}, t0);
    iter(TailT{}, t0);

    #pragma unroll
    for (int mt = 0; mt < 8; ++mt)
        #pragma unroll
        for (int nt = 0; nt < 4; ++nt)
            #pragma unroll
            for (int r = 0; r < 4; ++r) {
                const int row = bm0 + wm * 128 + mt * 16 + quad * 4 + r;
                const int col = bn0 + wn * 64 + nt * 16 + l15;
                if constexpr (F32OUT)
                    ((float*)Cv)[(size_t)row * N + col] = acc[mt][nt][r];
                else
                    ((short*)Cv)[(size_t)row * N + col] = f2bf(acc[mt][nt][r]);
            }
}

// ---------------------------------------------------------------------------
// Flash attention, causal, S^T formulation. q-tile 128 rows, 8 waves (512 thr).
// grid = 512 blocks; qt = b ? 15-t0 : t0 so co-resident pairs (ids +256) do
// constant 68 tiles. Waves 0-3 stage K (GLDS, XOR-swizzled), waves 4-7 stage V
// (transposed, pitch 40). Per-wave compute: 16 q-rows, S^T tiles.
#define VP 40
__global__ __launch_bounds__(512) void attn_kernel(const short* __restrict__ P,
                                                   short* __restrict__ O) {
    constexpr int S = 2048, ROWW = 6144, HD = 2048;
    const int id = blockIdx.x;
    const int b = id >> 8;
    const int rr = id & 255;
    const int h = rr & 15;
    const int t0 = rr >> 4;                    // 0..15
    const int qt = b ? (15 - t0) : t0;         // work balance across pairs
    const int wave = threadIdx.x >> 6, lane = threadIdx.x & 63;
    const int l15 = lane & 15, quad = lane >> 4;
    const int qRow = qt * 128 + wave * 16;
    const short* Pb = P + (size_t)b * S * ROWW;
    const short* Qp = Pb + h * 384;
    const short* Kp = Qp + 128;
    const short* Vp = Qp + 256;

    __shared__ short sK[2][32 * 128];   // swizzled chunk layout
    __shared__ short sVt[2][128 * VP];  // [d][key]

    // Q fragments (B operand, n=q=l15, k=d=quad*8+j)
    bf16x8 qf[4];
    #pragma unroll
    for (int f = 0; f < 4; f++)
        qf[f] = *(const bf16x8*)(Qp + (size_t)(qRow + l15) * ROWW + f * 32 + quad * 8);

    const bool isK = wave < 4;
    const int c1 = (wave & 3) * 64 + lane;
    const int krow1 = c1 >> 4;
    const int kcol = ((c1 & 15) ^ (krow1 & 15)) * 8;
    const short* gK1 = Kp + (size_t)krow1 * ROWW + kcol;
    const short* gK2 = Kp + (size_t)(krow1 + 16) * ROWW + kcol;
    const int ldsOff1 = (wave & 3) * 512;
    const int ldsOff2 = 2048 + (wave & 3) * 512;
    const int vt = (int)threadIdx.x - 256;
    const int vKey = vt & 31;
    const int vD0 = (vt >> 5) * 8;
    const short* gV = Vp + (size_t)vKey * ROWW + vD0;

    const int kTiles = qt * 4 + 4;
    const float scale = 0.08838834764831845f;  // 1/sqrt(128)
    const int qG = qRow + l15;

    f32x4 accO[8] = {};                        // O^T: row=d(quad*4+r), col=q(l15)
    float m_i = NEG_BIG, l_i = 0.f;

    if (isK) {
        GLDS16(gK1, &sK[0][ldsOff1]);
        GLDS16(gK2, &sK[0][ldsOff2]);
    } else {
        bf16x8 v0 = *(const bf16x8*)(gV);
        bf16x8 v1 = *(const bf16x8*)(gV + 64);
        #pragma unroll
        for (int j = 0; j < 8; j++) {
            sVt[0][(vD0 + j) * VP + vKey] = v0[j];
            sVt[0][(vD0 + 64 + j) * VP + vKey] = v1[j];
        }
    }
    __syncthreads();

    for (int kt = 0; kt < kTiles; kt++) {
        const int cur = kt & 1, nxt = cur ^ 1;
        const bool pre = (kt + 1 < kTiles);
        bf16x8 v0n, v1n;
        if (pre) {
            const size_t kOff = (size_t)(kt + 1) * 32 * ROWW;
            if (isK) {
                GLDS16(gK1 + kOff, &sK[nxt][ldsOff1]);
                GLDS16(gK2 + kOff, &sK[nxt][ldsOff2]);
            } else {
                v0n = *(const bf16x8*)(gV + kOff);
                v1n = *(const bf16x8*)(gV + kOff + 64);
            }
        }
        // QK^T transposed: sc[hh] row=key(quad*4+r), col=q(l15)
        f32x4 sc[2] = {};
        #pragma unroll
        for (int hh = 0; hh < 2; hh++) {
            const int row = hh * 16 + l15;
            #pragma unroll
            for (int f = 0; f < 4; f++) {
                const int jj = (4 * f + quad) ^ l15;
                bf16x8 kf = *(const bf16x8*)(&sK[cur][row * 128 + jj * 8]);
                sc[hh] = __builtin_amdgcn_mfma_f32_16x16x32_bf16(kf, qf[f], sc[hh], 0, 0, 0);
            }
        }
        #pragma unroll
        for (int hh = 0; hh < 2; hh++)
            #pragma unroll
            for (int r = 0; r < 4; r++) {
                int key = kt * 32 + hh * 16 + quad * 4 + r;
                float v = sc[hh][r] * scale;
                sc[hh][r] = (key <= qG) ? v : NEG_BIG;
            }
        float mloc = sc[0][0];
        #pragma unroll
        for (int r = 1; r < 4; r++) mloc = fmaxf(mloc, sc[0][r]);
        #pragma unroll
        for (int r = 0; r < 4; r++) mloc = fmaxf(mloc, sc[1][r]);
        mloc = fmaxf(mloc, __shfl_xor(mloc, 16));
        mloc = fmaxf(mloc, __shfl_xor(mloc, 32));
        const float nm = fmaxf(m_i, mloc);
        const float alpha = __expf(m_i - nm);
        m_i = nm;
        float ssum = 0.f;
        #pragma unroll
        for (int hh = 0; hh < 2; hh++)
            #pragma unroll
            for (int r = 0; r < 4; r++) {
                float p = __expf(sc[hh][r] - nm);
                sc[hh][r] = p;
                ssum += p;
            }
        ssum += __shfl_xor(ssum, 16);
        ssum += __shfl_xor(ssum, 32);
        l_i = alpha * l_i + ssum;
        #pragma unroll
        for (int t = 0; t < 8; t++)
            #pragma unroll
            for (int r = 0; r < 4; r++) accO[t][r] *= alpha;
        // P^T (C-layout) -> B-frag via 8 shfl
        const int d00 = pack2bf(sc[0][0], sc[0][1]);
        const int d01 = pack2bf(sc[0][2], sc[0][3]);
        const int d10 = pack2bf(sc[1][0], sc[1][1]);
        const int d11 = pack2bf(sc[1][2], sc[1][3]);
        const int srcA = l15 + ((quad & 1) << 5);
        const int srcB = srcA + 16;
        const int s00 = __shfl(d00, srcA), s01 = __shfl(d01, srcA);
        const int s02 = __shfl(d00, srcB), s03 = __shfl(d01, srcB);
        const int s10 = __shfl(d10, srcA), s11 = __shfl(d11, srcA);
        const int s12 = __shfl(d10, srcB), s13 = __shfl(d11, srcB);
        union { int i[4]; bf16x8 v; } pu;
        const bool lo = quad < 2;
        pu.i[0] = lo ? s00 : s10;
        pu.i[1] = lo ? s01 : s11;
        pu.i[2] = lo ? s02 : s12;
        pu.i[3] = lo ? s03 : s13;
        const bf16x8 pf = pu.v;
        // PV: O^T += V^T * P^T
        #pragma unroll
        for (int t = 0; t < 8; t++) {
            bf16x8 vf = *(const bf16x8*)(&sVt[cur][(t * 16 + l15) * VP + quad * 8]);
            accO[t] = __builtin_amdgcn_mfma_f32_16x16x32_bf16(vf, pf, accO[t], 0, 0, 0);
        }
        if (pre && !isK) {
            #pragma unroll
            for (int j = 0; j < 8; j++) {
                sVt[nxt][(vD0 + j) * VP + vKey] = v0n[j];
                sVt[nxt][(vD0 + 64 + j) * VP + vKey] = v1n[j];
            }
        }
        __syncthreads();
    }
    const float inv = 1.0f / l_i;
    #pragma unroll
    for (int t = 0; t < 8; t++) {
        short4 st;
        st.x = f2bf(accO[t][0] * inv);
        st.y = f2bf(accO[t][1] * inv);
        st.z = f2bf(accO[t][2] * inv);
        st.w = f2bf(accO[t][3] * inv);
        *(short4*)(&O[(size_t)(b * S + qG) * HD + h * 128 + t * 16 + quad * 4]) = st;
    }
}

extern "C" void kernel_launch(void* const* d_in, const int* in_sizes, int n_in,
                              void* d_out, int out_size, void* d_ws, size_t ws_size,
                              hipStream_t stream) {
    const float* x     = (const float*)d_in[0];  // [2,2048,2048] fp32
    const float* w_in  = (const float*)d_in[1];  // [6144,2048]  fp32
    const float* w_out = (const float*)d_in[2];  // [2048,2048]  fp32
    float* out = (float*)d_out;                  // [2,2048,2048] fp32

    // Workspace (96 MiB): P[4096*6144] bf16 | xO[8388608] bf16 (x_bf16 then O)
    //                     | w_in_b[6144*2048] bf16 | w_out_b[2048*2048] bf16
    short* Pbuf   = (short*)d_ws;
    short* xObuf  = Pbuf  + (size_t)4096 * 6144;
    short* winb   = xObuf + (size_t)8388608;
    short* woutb  = winb  + (size_t)6144 * 2048;

    dim3 blk(256, 1, 1);
    const int nx = 2 * 2048 * 2048, nwi = 6144 * 2048, nwo = 2048 * 2048;
    hipLaunchKernelGGL(cvt_f32_bf16, dim3(nx / 1024), blk, 0, stream, x, xObuf, nx);
    hipLaunchKernelGGL(cvt_f32_bf16, dim3(nwi / 1024), blk, 0, stream, w_in, winb, nwi);
    hipLaunchKernelGGL(cvt_f32_bf16, dim3(nwo / 1024), blk, 0, stream, w_out, woutb, nwo);
    // GEMM1: P = x @ w_in^T (M=4096, N=6144, K=2048), bf16 out — 8-phase 256²
    hipLaunchKernelGGL((gemm256<false>), dim3(384, 1, 1), dim3(512, 1, 1), 0, stream,
                       xObuf, winb, (void*)Pbuf, 6144, 2048, 16);
    // Flash attention (x_bf16 dead now; O overwrites it), 512 blocks x 512 thr
    hipLaunchKernelGGL(attn_kernel, dim3(512, 1, 1), dim3(512, 1, 1), 0, stream, Pbuf, xObuf);
    // GEMM2: out = O @ w_out^T (M=4096, N=2048, K=2048), fp32 out, BN=64 BK=64
    hipLaunchKernelGGL((gemm_bt<64, true>), dim3(32, 32, 1), blk, 0, stream, xObuf, woutb, (void*)out, 2048, 2048);
}

// Round 3
// 387.257 us; speedup vs baseline: 1.0513x; 1.0513x over previous
//
#include <hip/hip_runtime.h>
#include <hip/hip_bf16.h>
#include <math.h>

// Problem: Attention_58102317580396
// B=2, S=2048, D=2048, H=16, DH=128. Inputs/outputs FP32; internal bf16 MFMA.
// Pipeline: cvt(x,w_in,w_out)->bf16 ; GEMM1 x@w_in^T -> P[4096][6144] ;
//           flash attn -> O[4096][2048] ; GEMM2 O@w_out^T -> out fp32.
// R11: REVERT GEMM1 to gemm_bt<128> (measured 125.5us in R8; the 256x256
// 8-phase port is LDS-read-port-bound + 2-round quantized at this grid (384
// blocks, 1/CU) and measured 137-145us over two attempts — abandoned).
// GEMM2 upgraded BN=64 -> BN=128 (tile-space: 128^2 ~912 TF vs 64^2 ~343 TF
// at this structure; predict ~45us vs ~60+). Attn unchanged; with GEMM1 back
// at 125us, attn (~130-160us inferred, ~260 TF causal) should surface in the
// top-5 counters next round — it is the next rewrite target.
// Verified layouts (learn_hip m89/m120):
//   A-frag: m=lane&15, k=quad*8+j ; B-frag: n=lane&15, k=quad*8+j (same addr)
//   C/D:    col=lane&15, row=quad*4+reg

typedef short bf16x8 __attribute__((ext_vector_type(8)));
typedef float f32x4 __attribute__((ext_vector_type(4)));

#define NEG_BIG -30000.0f

__device__ __forceinline__ short f2bf(float f) {
    union { float f; unsigned u; } v; v.f = f;
    unsigned r = v.u + 0x7fffu + ((v.u >> 16) & 1u);  // RNE
    return (short)(r >> 16);
}

__device__ __forceinline__ int pack2bf(float a, float b) {
    return (int)((((unsigned)f2bf(b)) << 16) | (((unsigned)f2bf(a)) & 0xffffu));
}

#define GLDS16(g, l) \
    __builtin_amdgcn_global_load_lds((const __attribute__((address_space(1))) void*)(g), \
                                     (__attribute__((address_space(3))) void*)(l), 16, 0, 0)

// fp32 -> bf16 elementwise (n divisible by 1024)
__global__ __launch_bounds__(256) void cvt_f32_bf16(const float* __restrict__ src,
                                                    short* __restrict__ dst, int n) {
    int i = (blockIdx.x * blockDim.x + threadIdx.x) * 4;
    if (i < n) {
        float4 v = *(const float4*)(src + i);
        short4 o;
        o.x = f2bf(v.x); o.y = f2bf(v.y); o.z = f2bf(v.z); o.w = f2bf(v.w);
        *(short4*)(dst + i) = o;
    }
}

// C[M][N] = A[M][K] * B[N][K]^T  (bf16 in, fp32 acc, bf16 or fp32 out)
// block 256 = 4 waves; block tile 128xBN; wave tile 64x(BN/2); BK=64 as two
// 32-k sub-tiles per barrier pair. LDS layout per sub: chunk-ordered rows x32.
template <int BN, bool F32OUT>
__global__ __launch_bounds__(256) void gemm_bt(const short* __restrict__ A,
                                               const short* __restrict__ Bm,
                                               void* __restrict__ Cv,
                                               int N, int K) {
    constexpr int NT = BN / 32;               // n-acc tiles per wave
    constexpr int SUBA = 128 * 32;            // shorts per A sub-tile
    constexpr int SUBB = BN * 32;             // shorts per B sub-tile
    __shared__ short sA[2 * SUBA];
    __shared__ short sB[2 * SUBB];
    const int lane = threadIdx.x & 63;
    const int w = threadIdx.x >> 6;
    const int l15 = lane & 15, quad = lane >> 4;
    const int bm0 = blockIdx.y * 128, bn0 = blockIdx.x * BN;

    const int c1 = w * 64 + lane;             // chunk id 0..255
    const short* gA = A + (size_t)(bm0 + (c1 >> 2)) * K + (c1 & 3) * 8;
    const short* gB = Bm + (size_t)(bn0 + (c1 >> 2)) * K + (c1 & 3) * 8;
    const size_t half64 = (size_t)64 * K;     // chunk +256 -> row +64
    short* lA1 = sA + w * 512;                // wave-uniform GLDS bases
    short* lA2 = sA + 2048 + w * 512;
    short* lB1 = sB + w * 512;
    short* lB2 = sB + 2048 + w * 512;         // only when BN==128

    const int wm = (w >> 1) * 64, wn = (w & 1) * (BN / 2);
    const short* pa = sA + (wm + l15) * 32 + quad * 8;
    const short* pb = sB + (wn + l15) * 32 + quad * 8;

    f32x4 acc[4][NT] = {};
    for (int k0 = 0; k0 < K; k0 += 64) {
        #pragma unroll
        for (int s = 0; s < 2; s++) {
            const int ks = k0 + s * 32;
            GLDS16(gA + ks, lA1 + s * SUBA);
            GLDS16(gA + half64 + ks, lA2 + s * SUBA);
            GLDS16(gB + ks, lB1 + s * SUBB);
            if constexpr (BN == 128) GLDS16(gB + half64 + ks, lB2 + s * SUBB);
        }
        __syncthreads();
        #pragma unroll
        for (int s = 0; s < 2; s++) {
            bf16x8 af[4], bf[NT];
            #pragma unroll
            for (int mt = 0; mt < 4; mt++) af[mt] = *(const bf16x8*)(pa + s * SUBA + mt * 512);
            #pragma unroll
            for (int nt = 0; nt < NT; nt++) bf[nt] = *(const bf16x8*)(pb + s * SUBB + nt * 512);
            #pragma unroll
            for (int mt = 0; mt < 4; mt++)
                #pragma unroll
                for (int nt = 0; nt < NT; nt++)
                    acc[mt][nt] = __builtin_amdgcn_mfma_f32_16x16x32_bf16(af[mt], bf[nt], acc[mt][nt], 0, 0, 0);
        }
        __syncthreads();
    }
    #pragma unroll
    for (int mt = 0; mt < 4; mt++)
        #pragma unroll
        for (int nt = 0; nt < NT; nt++)
            #pragma unroll
            for (int r = 0; r < 4; r++) {
                int row = bm0 + wm + mt * 16 + quad * 4 + r;
                int col = bn0 + wn + nt * 16 + l15;
                if (F32OUT)
                    ((float*)Cv)[(size_t)row * N + col] = acc[mt][nt][r];
                else
                    ((short*)Cv)[(size_t)row * N + col] = f2bf(acc[mt][nt][r]);
            }
}

// ---------------------------------------------------------------------------
// Flash attention, causal, S^T formulation. q-tile 128 rows, 8 waves (512 thr).
// grid = 512 blocks; qt = b ? 15-t0 : t0 so co-resident pairs (ids +256) do
// constant 68 tiles. Waves 0-3 stage K (GLDS, XOR-swizzled), waves 4-7 stage V
// (transposed, pitch 40). Per-wave compute: 16 q-rows, S^T tiles.
#define VP 40
__global__ __launch_bounds__(512) void attn_kernel(const short* __restrict__ P,
                                                   short* __restrict__ O) {
    constexpr int S = 2048, ROWW = 6144, HD = 2048;
    const int id = blockIdx.x;
    const int b = id >> 8;
    const int rr = id & 255;
    const int h = rr & 15;
    const int t0 = rr >> 4;                    // 0..15
    const int qt = b ? (15 - t0) : t0;         // work balance across pairs
    const int wave = threadIdx.x >> 6, lane = threadIdx.x & 63;
    const int l15 = lane & 15, quad = lane >> 4;
    const int qRow = qt * 128 + wave * 16;
    const short* Pb = P + (size_t)b * S * ROWW;
    const short* Qp = Pb + h * 384;
    const short* Kp = Qp + 128;
    const short* Vp = Qp + 256;

    __shared__ short sK[2][32 * 128];   // swizzled chunk layout
    __shared__ short sVt[2][128 * VP];  // [d][key]

    // Q fragments (B operand, n=q=l15, k=d=quad*8+j)
    bf16x8 qf[4];
    #pragma unroll
    for (int f = 0; f < 4; f++)
        qf[f] = *(const bf16x8*)(Qp + (size_t)(qRow + l15) * ROWW + f * 32 + quad * 8);

    const bool isK = wave < 4;
    const int c1 = (wave & 3) * 64 + lane;
    const int krow1 = c1 >> 4;
    const int kcol = ((c1 & 15) ^ (krow1 & 15)) * 8;
    const short* gK1 = Kp + (size_t)krow1 * ROWW + kcol;
    const short* gK2 = Kp + (size_t)(krow1 + 16) * ROWW + kcol;
    const int ldsOff1 = (wave & 3) * 512;
    const int ldsOff2 = 2048 + (wave & 3) * 512;
    const int vt = (int)threadIdx.x - 256;
    const int vKey = vt & 31;
    const int vD0 = (vt >> 5) * 8;
    const short* gV = Vp + (size_t)vKey * ROWW + vD0;

    const int kTiles = qt * 4 + 4;
    const float scale = 0.08838834764831845f;  // 1/sqrt(128)
    const int qG = qRow + l15;

    f32x4 accO[8] = {};                        // O^T: row=d(quad*4+r), col=q(l15)
    float m_i = NEG_BIG, l_i = 0.f;

    if (isK) {
        GLDS16(gK1, &sK[0][ldsOff1]);
        GLDS16(gK2, &sK[0][ldsOff2]);
    } else {
        bf16x8 v0 = *(const bf16x8*)(gV);
        bf16x8 v1 = *(const bf16x8*)(gV + 64);
        #pragma unroll
        for (int j = 0; j < 8; j++) {
            sVt[0][(vD0 + j) * VP + vKey] = v0[j];
            sVt[0][(vD0 + 64 + j) * VP + vKey] = v1[j];
        }
    }
    __syncthreads();

    for (int kt = 0; kt < kTiles; kt++) {
        const int cur = kt & 1, nxt = cur ^ 1;
        const bool pre = (kt + 1 < kTiles);
        bf16x8 v0n, v1n;
        if (pre) {
            const size_t kOff = (size_t)(kt + 1) * 32 * ROWW;
            if (isK) {
                GLDS16(gK1 + kOff, &sK[nxt][ldsOff1]);
                GLDS16(gK2 + kOff, &sK[nxt][ldsOff2]);
            } else {
                v0n = *(const bf16x8*)(gV + kOff);
                v1n = *(const bf16x8*)(gV + kOff + 64);
            }
        }
        // QK^T transposed: sc[hh] row=key(quad*4+r), col=q(l15)
        f32x4 sc[2] = {};
        #pragma unroll
        for (int hh = 0; hh < 2; hh++) {
            const int row = hh * 16 + l15;
            #pragma unroll
            for (int f = 0; f < 4; f++) {
                const int jj = (4 * f + quad) ^ l15;
                bf16x8 kf = *(const bf16x8*)(&sK[cur][row * 128 + jj * 8]);
                sc[hh] = __builtin_amdgcn_mfma_f32_16x16x32_bf16(kf, qf[f], sc[hh], 0, 0, 0);
            }
        }
        #pragma unroll
        for (int hh = 0; hh < 2; hh++)
            #pragma unroll
            for (int r = 0; r < 4; r++) {
                int key = kt * 32 + hh * 16 + quad * 4 + r;
                float v = sc[hh][r] * scale;
                sc[hh][r] = (key <= qG) ? v : NEG_BIG;
            }
        float mloc = sc[0][0];
        #pragma unroll
        for (int r = 1; r < 4; r++) mloc = fmaxf(mloc, sc[0][r]);
        #pragma unroll
        for (int r = 0; r < 4; r++) mloc = fmaxf(mloc, sc[1][r]);
        mloc = fmaxf(mloc, __shfl_xor(mloc, 16));
        mloc = fmaxf(mloc, __shfl_xor(mloc, 32));
        const float nm = fmaxf(m_i, mloc);
        const float alpha = __expf(m_i - nm);
        m_i = nm;
        float ssum = 0.f;
        #pragma unroll
        for (int hh = 0; hh < 2; hh++)
            #pragma unroll
            for (int r = 0; r < 4; r++) {
                float p = __expf(sc[hh][r] - nm);
                sc[hh][r] = p;
                ssum += p;
            }
        ssum += __shfl_xor(ssum, 16);
        ssum += __shfl_xor(ssum, 32);
        l_i = alpha * l_i + ssum;
        #pragma unroll
        for (int t = 0; t < 8; t++)
            #pragma unroll
            for (int r = 0; r < 4; r++) accO[t][r] *= alpha;
        // P^T (C-layout) -> B-frag via 8 shfl
        const int d00 = pack2bf(sc[0][0], sc[0][1]);
        const int d01 = pack2bf(sc[0][2], sc[0][3]);
        const int d10 = pack2bf(sc[1][0], sc[1][1]);
        const int d11 = pack2bf(sc[1][2], sc[1][3]);
        const int srcA = l15 + ((quad & 1) << 5);
        const int srcB = srcA + 16;
        const int s00 = __shfl(d00, srcA), s01 = __shfl(d01, srcA);
        const int s02 = __shfl(d00, srcB), s03 = __shfl(d01, srcB);
        const int s10 = __shfl(d10, srcA), s11 = __shfl(d11, srcA);
        const int s12 = __shfl(d10, srcB), s13 = __shfl(d11, srcB);
        union { int i[4]; bf16x8 v; } pu;
        const bool lo = quad < 2;
        pu.i[0] = lo ? s00 : s10;
        pu.i[1] = lo ? s01 : s11;
        pu.i[2] = lo ? s02 : s12;
        pu.i[3] = lo ? s03 : s13;
        const bf16x8 pf = pu.v;
        // PV: O^T += V^T * P^T
        #pragma unroll
        for (int t = 0; t < 8; t++) {
            bf16x8 vf = *(const bf16x8*)(&sVt[cur][(t * 16 + l15) * VP + quad * 8]);
            accO[t] = __builtin_amdgcn_mfma_f32_16x16x32_bf16(vf, pf, accO[t], 0, 0, 0);
        }
        if (pre && !isK) {
            #pragma unroll
            for (int j = 0; j < 8; j++) {
                sVt[nxt][(vD0 + j) * VP + vKey] = v0n[j];
                sVt[nxt][(vD0 + 64 + j) * VP + vKey] = v1n[j];
            }
        }
        __syncthreads();
    }
    const float inv = 1.0f / l_i;
    #pragma unroll
    for (int t = 0; t < 8; t++) {
        short4 st;
        st.x = f2bf(accO[t][0] * inv);
        st.y = f2bf(accO[t][1] * inv);
        st.z = f2bf(accO[t][2] * inv);
        st.w = f2bf(accO[t][3] * inv);
        *(short4*)(&O[(size_t)(b * S + qG) * HD + h * 128 + t * 16 + quad * 4]) = st;
    }
}

extern "C" void kernel_launch(void* const* d_in, const int* in_sizes, int n_in,
                              void* d_out, int out_size, void* d_ws, size_t ws_size,
                              hipStream_t stream) {
    const float* x     = (const float*)d_in[0];  // [2,2048,2048] fp32
    const float* w_in  = (const float*)d_in[1];  // [6144,2048]  fp32
    const float* w_out = (const float*)d_in[2];  // [2048,2048]  fp32
    float* out = (float*)d_out;                  // [2,2048,2048] fp32

    // Workspace (96 MiB): P[4096*6144] bf16 | xO[8388608] bf16 (x_bf16 then O)
    //                     | w_in_b[6144*2048] bf16 | w_out_b[2048*2048] bf16
    short* Pbuf   = (short*)d_ws;
    short* xObuf  = Pbuf  + (size_t)4096 * 6144;
    short* winb   = xObuf + (size_t)8388608;
    short* woutb  = winb  + (size_t)6144 * 2048;

    dim3 blk(256, 1, 1);
    const int nx = 2 * 2048 * 2048, nwi = 6144 * 2048, nwo = 2048 * 2048;
    hipLaunchKernelGGL(cvt_f32_bf16, dim3(nx / 1024), blk, 0, stream, x, xObuf, nx);
    hipLaunchKernelGGL(cvt_f32_bf16, dim3(nwi / 1024), blk, 0, stream, w_in, winb, nwi);
    hipLaunchKernelGGL(cvt_f32_bf16, dim3(nwo / 1024), blk, 0, stream, w_out, woutb, nwo);
    // GEMM1: P = x @ w_in^T   (M=4096, N=6144, K=2048), bf16 out, BN=128 BK=64
    hipLaunchKernelGGL((gemm_bt<128, false>), dim3(48, 32, 1), blk, 0, stream, xObuf, winb, (void*)Pbuf, 6144, 2048);
    // Flash attention (x_bf16 dead now; O overwrites it), 512 blocks x 512 thr
    hipLaunchKernelGGL(attn_kernel, dim3(512, 1, 1), dim3(512, 1, 1), 0, stream, Pbuf, xObuf);
    // GEMM2: out = O @ w_out^T (M=4096, N=2048, K=2048), fp32 out, BN=128 BK=64
    hipLaunchKernelGGL((gemm_bt<128, true>), dim3(16, 32, 1), blk, 0, stream, xObuf, woutb, (void*)out, 2048, 2048);
}